// Round 8
// baseline (376.744 us; speedup 1.0000x reference)
//
#include <hip/hip_runtime.h>
#include <hip/hip_bf16.h>
#include <math.h>

// ---------------------------------------------------------------------------
// Problem constants: B=8, S=1024, D=768, F=3072, H=12, d_k=64
// ---------------------------------------------------------------------------
#define BB 8
#define SS 1024
#define DD 768
#define FF 3072
#define HH 12
#define DK 64

typedef __bf16 bf16;
typedef __attribute__((ext_vector_type(8))) __bf16 bf16x8;
typedef __attribute__((ext_vector_type(4))) __bf16 bf16x4;
typedef __attribute__((ext_vector_type(4))) float f32x4;

#define AS1 __attribute__((address_space(1)))
#define AS3 __attribute__((address_space(3)))

// exp(x) = exp2(x * log2e); fold 1/sqrt(64)=0.125 in: exp(s*0.125)
#define EXP2_SCALE 0.18033688011112042f   // 0.125 * log2(e)
#define NLOG2E2    -2.8853900817779268f   // -2 * log2(e)
#define MASK_BIAS  -1.8e8f                // ~ -1e9 * EXP2_SCALE; exp2 -> 0

// fast tanh-GELU: 0.5x(1+tanh(u)) == x * sigmoid(2u), exact identity.
__device__ __forceinline__ float gelu_fast(float x) {
    const float u = 0.7978845608028654f * (x + 0.044715f * x * x * x);
    const float e = __builtin_amdgcn_exp2f(u * NLOG2E2);   // exp(-2u)
    return x * __builtin_amdgcn_rcpf(1.0f + e);
}

// ---------------------------------------------------------------------------
// bf16 MFMA GEMM: C[M,N] = A[M,K] @ Bt[N,K]^T + bias (+ R).
// BM=128, BN template {128,64}, BK=64, 256 threads,
// global_load_lds w16 + XOR swizzle, 16x16x32 bf16 MFMA.
// 1-D grid, m-tile FASTEST (stride M/128 = mult of 8 -> same XCD -> A reuse).
// RB: residual dtype (0=f32, 1=bf16).
// ---------------------------------------------------------------------------
template<int BN, int OUTB, int GELU_F, int RESID, int RB>
__global__ __launch_bounds__(256) void gemm_bf16(
    const bf16* __restrict__ A, const bf16* __restrict__ Bt,
    const float* __restrict__ bias, const void* __restrict__ R,
    void* __restrict__ Cout, int M, int N, int K)
{
    constexpr int NTJ   = BN / 32;        // wave n-tiles (4 or 2)
    constexpr int BITER = (BN * 8) / 256; // B staging rounds (4 or 2)

    __shared__ bf16x8 As[1024];           // 128 rows x 8 chunks
    __shared__ bf16x8 Bs[BN * 8];

    const int t    = threadIdx.x;
    const int wave = t >> 6;
    const int lane = t & 63;
    const int mtiles = M >> 7;
    const int m0 = (blockIdx.x % mtiles) * 128;   // m fastest
    const int n0 = (blockIdx.x / mtiles) * BN;
    const int wm = (wave >> 1) * 64;
    const int wn = (wave & 1) * (BN / 2);
    const int col  = lane & 15;
    const int quad = lane >> 4;

    f32x4 acc[4][NTJ] = {};

    const bf16* Abase = A  + (size_t)m0 * K;
    const bf16* Bbase = Bt + (size_t)n0 * K;

    for (int k0 = 0; k0 < K; k0 += 64) {
        if (k0) __syncthreads();

        #pragma unroll
        for (int i = 0; i < 4; ++i) {
            const int chunk = i * 256 + wave * 64 + lane;
            const int r  = chunk >> 3;
            const int kc = (chunk & 7) ^ (r & 7);
            const bf16* ga = Abase + (size_t)r * K + k0 + kc * 8;
            __builtin_amdgcn_global_load_lds((AS1 void*)ga, (AS3 void*)(As + i * 256 + wave * 64), 16, 0, 0);
        }
        #pragma unroll
        for (int i = 0; i < BITER; ++i) {
            const int chunk = i * 256 + wave * 64 + lane;
            const int r  = chunk >> 3;
            const int kc = (chunk & 7) ^ (r & 7);
            const bf16* gb = Bbase + (size_t)r * K + k0 + kc * 8;
            __builtin_amdgcn_global_load_lds((AS1 void*)gb, (AS3 void*)(Bs + i * 256 + wave * 64), 16, 0, 0);
        }
        __syncthreads();

        const bf16* Asp = (const bf16*)As;
        const bf16* Bsp = (const bf16*)Bs;
        #pragma unroll
        for (int ks = 0; ks < 2; ++ks) {
            bf16x8 af[4], bfr[NTJ];
            #pragma unroll
            for (int ti = 0; ti < 4; ++ti) {
                const int r  = wm + ti * 16 + col;
                const int cs = (ks * 4 + quad) ^ (r & 7);
                af[ti] = *(const bf16x8*)(Asp + r * 64 + cs * 8);
            }
            #pragma unroll
            for (int tj = 0; tj < NTJ; ++tj) {
                const int r  = wn + tj * 16 + col;
                const int cs = (ks * 4 + quad) ^ (r & 7);
                bfr[tj] = *(const bf16x8*)(Bsp + r * 64 + cs * 8);
            }
            #pragma unroll
            for (int ti = 0; ti < 4; ++ti)
                #pragma unroll
                for (int tj = 0; tj < NTJ; ++tj)
                    acc[ti][tj] = __builtin_amdgcn_mfma_f32_16x16x32_bf16(
                        af[ti], bfr[tj], acc[ti][tj], 0, 0, 0);
        }
    }

    float biasv[NTJ];
    #pragma unroll
    for (int tj = 0; tj < NTJ; ++tj) biasv[tj] = bias[n0 + wn + tj * 16 + col];

    #pragma unroll
    for (int ti = 0; ti < 4; ++ti) {
        #pragma unroll
        for (int tj = 0; tj < NTJ; ++tj) {
            const int n = n0 + wn + tj * 16 + col;
            #pragma unroll
            for (int i = 0; i < 4; ++i) {
                const int m = m0 + wm + ti * 16 + quad * 4 + i;
                float v = acc[ti][tj][i] + biasv[tj];
                if (GELU_F) v = gelu_fast(v);
                if (RESID) {
                    const size_t idx = (size_t)m * N + n;
                    v += RB ? (float)((const bf16*)R)[idx]
                            : ((const float*)R)[idx];
                }
                if (OUTB) ((bf16*)Cout)[(size_t)m * N + n] = (bf16)v;
                else      ((float*)Cout)[(size_t)m * N + n] = v;
            }
        }
    }
}

// ---------------------------------------------------------------------------
// Batched prep: 6 weight transpose+casts, bias concat, x cast — ONE launch.
// ---------------------------------------------------------------------------
__device__ __forceinline__ void tc32(
    const float* __restrict__ src, bf16* __restrict__ dst,
    int R, int C, int c0, int r0, int t)
{
    __shared__ float tile[32][33];
    const int tx = t & 31, ty = t >> 5;
    #pragma unroll
    for (int i = 0; i < 32; i += 8)
        tile[ty + i][tx] = src[(size_t)(r0 + ty + i) * C + c0 + tx];
    __syncthreads();
    #pragma unroll
    for (int i = 0; i < 32; i += 8)
        dst[(size_t)(c0 + ty + i) * R + r0 + tx] = (bf16)tile[tx][ty + i];
}

__global__ __launch_bounds__(256) void prep_all(
    const float* __restrict__ Wq, const float* __restrict__ Wk,
    const float* __restrict__ Wv, const float* __restrict__ Wo,
    const float* __restrict__ W1, const float* __restrict__ W2,
    const float* __restrict__ bq, const float* __restrict__ bk,
    const float* __restrict__ bv, const float* __restrict__ x,
    bf16* __restrict__ wqkvb, bf16* __restrict__ wob,
    bf16* __restrict__ wt1b,  bf16* __restrict__ wt2b,
    float* __restrict__ bqkv, bf16x4* __restrict__ xb)
{
    const int blk = blockIdx.x;
    const int t = threadIdx.x;
    if (blk < 2304) {
        const int job = blk / 576, loc = blk % 576;
        const int c0 = (loc % 24) * 32, r0 = (loc / 24) * 32;
        const float* src = (job == 0) ? Wq : (job == 1) ? Wk : (job == 2) ? Wv : Wo;
        bf16* dst = (job == 3) ? wob : wqkvb + (size_t)job * DD * DD;
        tc32(src, dst, DD, DD, c0, r0, t);
    } else if (blk < 4608) {
        const int loc = blk - 2304;
        tc32(W1, wt1b, DD, FF, (loc % 96) * 32, (loc / 96) * 32, t);
    } else if (blk < 6912) {
        const int loc = blk - 4608;
        tc32(W2, wt2b, FF, DD, (loc % 24) * 32, (loc / 24) * 32, t);
    } else if (blk < 6921) {
        const int i = (blk - 6912) * 256 + t;
        if (i < 3 * DD)
            bqkv[i] = (i < DD) ? bq[i] : (i < 2 * DD ? bk[i - DD] : bv[i - 2 * DD]);
    } else {
        const int i = (blk - 6921) * 256 + t;
        const float4 v = ((const float4*)x)[i];
        bf16x4 o;
        o.x = (bf16)v.x; o.y = (bf16)v.y; o.z = (bf16)v.z; o.w = (bf16)v.w;
        xb[i] = o;
    }
}

// ---------------------------------------------------------------------------
// V transpose: qkvb V-slice [b*S+s][1536+h*64+d] -> vtb[(b*H+h)*64+d][s] bf16
// ---------------------------------------------------------------------------
__global__ __launch_bounds__(256) void vtrans(
    const bf16* __restrict__ qkvb, bf16* __restrict__ vtb)
{
    __shared__ bf16 tile[32][33];
    const int s0 = blockIdx.x * 32, d0 = blockIdx.y * 32;
    const int bh = blockIdx.z;
    const int b = bh / HH, h = bh % HH;
    const int tx = threadIdx.x & 31, ty = threadIdx.x >> 5;
    #pragma unroll
    for (int i = 0; i < 32; i += 8)
        tile[ty + i][tx] = qkvb[(size_t)(b * SS + s0 + ty + i) * 2304 + 1536 + h * DK + d0 + tx];
    __syncthreads();
    #pragma unroll
    for (int i = 0; i < 32; i += 8)
        vtb[(size_t)(bh * DK + d0 + ty + i) * SS + s0 + tx] = tile[tx][ty + i];
}

// ---------------------------------------------------------------------------
// MFMA flash attention, no-max-shift softmax. Block = 128 q-rows of one
// (b,h). Staging granularity: 128 columns (two 64-col halves) per barrier
// pair -> half the barrier drains of the 64-col version. Mask folded into
// exp via fma bias. 1-D grid, bh FASTEST (stride 96 -> same XCD).
// LDS: Ks 16KB + Vs 16KB + Ps 16KB = 48KB.
// ---------------------------------------------------------------------------
__global__ __launch_bounds__(256) void flash_mfma(
    const bf16* __restrict__ qkvb,   // [M,2304] bf16
    const bf16* __restrict__ vtb,    // [96*64, 1024] bf16
    const int*  __restrict__ mask,   // [B*S]
    bf16* __restrict__ O)            // [M,768] bf16
{
    __shared__ bf16x8 Ks[1024];       // two 64x64 K-tiles
    __shared__ bf16x8 Vs[1024];       // two 64x64 Vt-tiles
    __shared__ bf16   Ps[4 * 32 * 64];

    const int t    = threadIdx.x;
    const int wave = t >> 6;
    const int lane = t & 63;
    const int col  = lane & 15;
    const int quad = lane >> 4;
    const int bh = blockIdx.x % (BB * HH);       // bh fastest
    const int q0 = (blockIdx.x / (BB * HH)) * 128;
    const int b  = bh / HH;
    const int h  = bh % HH;

    bf16x8 aq[2][2];
    #pragma unroll
    for (int mi = 0; mi < 2; ++mi)
        #pragma unroll
        for (int ks = 0; ks < 2; ++ks)
            aq[mi][ks] = *(const bf16x8*)(qkvb
                + (size_t)(b * SS + q0 + wave * 32 + mi * 16 + col) * 2304
                + h * DK + ks * 32 + quad * 8);

    f32x4 o[2][4] = {};
    float l_part[2][4] = {};

    bf16* Pw = Ps + wave * 2048;

    for (int c0 = 0; c0 < SS; c0 += 128) {
        if (c0) __syncthreads();

        // stage two 64-col K tiles and two 64-col Vt tiles, XOR-swizzled
        #pragma unroll
        for (int i = 0; i < 4; ++i) {
            const int chunk = i * 256 + wave * 64 + lane;   // 0..1023
            const int half  = chunk >> 9;
            const int wi    = chunk & 511;
            const int r  = wi >> 3;
            const int kc = (wi & 7) ^ (r & 7);
            const bf16* gk = qkvb + (size_t)(b * SS + c0 + half * 64 + r) * 2304
                           + DD + h * DK + kc * 8;
            __builtin_amdgcn_global_load_lds((AS1 void*)gk, (AS3 void*)(Ks + chunk - lane + lane), 16, 0, 0);
        }
        #pragma unroll
        for (int i = 0; i < 4; ++i) {
            const int chunk = i * 256 + wave * 64 + lane;
            const int half  = chunk >> 9;
            const int wi    = chunk & 511;
            const int r  = wi >> 3;
            const int kc = (wi & 7) ^ (r & 7);
            const bf16* gv = vtb + (size_t)(bh * DK + r) * SS + c0 + half * 64 + kc * 8;
            __builtin_amdgcn_global_load_lds((AS1 void*)gv, (AS3 void*)(Vs + chunk - lane + lane), 16, 0, 0);
        }
        __syncthreads();

        #pragma unroll
        for (int half = 0; half < 2; ++half) {
            const bf16* Ksp = (const bf16*)(Ks + half * 512);
            const bf16* Vsp = (const bf16*)(Vs + half * 512);
            const int ch0 = c0 + half * 64;

            // ---- S = Q K^T ----
            f32x4 s4[2][4] = {};
            {
                bf16x8 kf[2][4];
                #pragma unroll
                for (int ks = 0; ks < 2; ++ks)
                    #pragma unroll
                    for (int tj = 0; tj < 4; ++tj) {
                        const int r  = tj * 16 + col;
                        const int sl = (ks * 4 + quad) ^ (r & 7);
                        kf[ks][tj] = *(const bf16x8*)(Ksp + r * 64 + sl * 8);
                    }
                #pragma unroll
                for (int mi = 0; mi < 2; ++mi)
                    #pragma unroll
                    for (int ks = 0; ks < 2; ++ks)
                        #pragma unroll
                        for (int tj = 0; tj < 4; ++tj)
                            s4[mi][tj] = __builtin_amdgcn_mfma_f32_16x16x32_bf16(
                                aq[mi][ks], kf[ks][tj], s4[mi][tj], 0, 0, 0);
            }

            // ---- P = exp(S*scale + maskbias), accumulate row-sum partials
            float addb[4];
            #pragma unroll
            for (int tj = 0; tj < 4; ++tj)
                addb[tj] = mask[b * SS + ch0 + tj * 16 + col] ? 0.0f : MASK_BIAS;

            #pragma unroll
            for (int mi = 0; mi < 2; ++mi)
                #pragma unroll
                for (int i = 0; i < 4; ++i) {
                    const int rf = mi * 16 + quad * 4 + i;
                    #pragma unroll
                    for (int tj = 0; tj < 4; ++tj) {
                        const float p = __builtin_amdgcn_exp2f(
                            fmaf(s4[mi][tj][i], EXP2_SCALE, addb[tj]));
                        l_part[mi][i] += p;
                        const int c  = tj * 16 + col;
                        const int sl = ((c >> 3) ^ (rf & 7));
                        Pw[rf * 64 + sl * 8 + (c & 7)] = (bf16)p;
                    }
                }

            // ---- O += P V ----
            bf16x8 vf[2][4];
            #pragma unroll
            for (int ks = 0; ks < 2; ++ks)
                #pragma unroll
                for (int tj = 0; tj < 4; ++tj) {
                    const int r  = tj * 16 + col;
                    const int sl = (ks * 4 + quad) ^ (r & 7);
                    vf[ks][tj] = *(const bf16x8*)(Vsp + r * 64 + sl * 8);
                }
            #pragma unroll
            for (int mi = 0; mi < 2; ++mi) {
                bf16x8 pf[2];
                #pragma unroll
                for (int ks = 0; ks < 2; ++ks) {
                    const int rf = mi * 16 + col;
                    const int sl = (ks * 4 + quad) ^ (rf & 7);
                    pf[ks] = *(const bf16x8*)(Pw + rf * 64 + sl * 8);
                }
                #pragma unroll
                for (int ks = 0; ks < 2; ++ks)
                    #pragma unroll
                    for (int tj = 0; tj < 4; ++tj)
                        o[mi][tj] = __builtin_amdgcn_mfma_f32_16x16x32_bf16(
                            pf[ks], vf[ks][tj], o[mi][tj], 0, 0, 0);
            }
        }
    }

    #pragma unroll
    for (int mi = 0; mi < 2; ++mi)
        #pragma unroll
        for (int i = 0; i < 4; ++i) {
            float l = l_part[mi][i];
            #pragma unroll
            for (int off = 1; off < 16; off <<= 1)
                l += __shfl_xor(l, off, 64);
            const float inv = 1.0f / l;
            const int q = q0 + wave * 32 + mi * 16 + quad * 4 + i;
            #pragma unroll
            for (int tj = 0; tj < 4; ++tj)
                O[(size_t)(b * SS + q) * DD + h * DK + tj * 16 + col] =
                    (bf16)(o[mi][tj][i] * inv);
        }
}

// ---------------------------------------------------------------------------
// LayerNorm (torch-style: unbiased var, eps on std). bf16 input.
// Optional fp32 and bf16 outputs (either may be null).
// ---------------------------------------------------------------------------
__global__ __launch_bounds__(256) void layernorm_k(
    const bf16* __restrict__ X,
    const float* __restrict__ ga, const float* __restrict__ gb,
    float* __restrict__ out, bf16* __restrict__ outb)
{
    __shared__ float red[4];
    const int row = blockIdx.x;
    const int t   = threadIdx.x;
    const bf16* x = X + (size_t)row * DD;

    float v[3];
    #pragma unroll
    for (int i = 0; i < 3; ++i) v[i] = (float)x[t + i * 256];

    float s = v[0] + v[1] + v[2];
    #pragma unroll
    for (int off = 32; off > 0; off >>= 1) s += __shfl_down(s, off, 64);
    if ((t & 63) == 0) red[t >> 6] = s;
    __syncthreads();
    const float mean = (red[0] + red[1] + red[2] + red[3]) * (1.0f / 768.0f);
    __syncthreads();

    float sq = 0.f;
    #pragma unroll
    for (int i = 0; i < 3; ++i) { const float d = v[i] - mean; sq += d * d; }
    #pragma unroll
    for (int off = 32; off > 0; off >>= 1) sq += __shfl_down(sq, off, 64);
    if ((t & 63) == 0) red[t >> 6] = sq;
    __syncthreads();
    const float var = (red[0] + red[1] + red[2] + red[3]) * (1.0f / 767.0f);
    const float inv = 1.0f / (sqrtf(var) + 1e-6f);

    #pragma unroll
    for (int i = 0; i < 3; ++i) {
        const int c = t + i * 256;
        const float r = ga[c] * (v[i] - mean) * inv + gb[c];
        if (out)  out[(size_t)row * DD + c] = r;
        if (outb) outb[(size_t)row * DD + c] = (bf16)r;
    }
}

// ---------------------------------------------------------------------------
// Launch
// ---------------------------------------------------------------------------
extern "C" void kernel_launch(void* const* d_in, const int* in_sizes, int n_in,
                              void* d_out, int out_size, void* d_ws, size_t ws_size,
                              hipStream_t stream)
{
    const float* x    = (const float*)d_in[0];
    const int*   mask = (const int*)  d_in[1];
    const float* Wq   = (const float*)d_in[2];
    const float* bq   = (const float*)d_in[3];
    const float* Wk   = (const float*)d_in[4];
    const float* bk   = (const float*)d_in[5];
    const float* Wv   = (const float*)d_in[6];
    const float* bv   = (const float*)d_in[7];
    const float* Wo   = (const float*)d_in[8];
    const float* bo   = (const float*)d_in[9];
    const float* W1   = (const float*)d_in[10];
    const float* b1   = (const float*)d_in[11];
    const float* W2   = (const float*)d_in[12];
    const float* b2   = (const float*)d_in[13];
    const float* ln1a = (const float*)d_in[14];
    const float* ln1b = (const float*)d_in[15];
    const float* ln2a = (const float*)d_in[16];
    const float* ln2b = (const float*)d_in[17];
    float* out = (float*)d_out;

    const int M = BB * SS;                       // 8192
    const size_t nBSD = (size_t)M * DD;

    char* w = (char*)d_ws;
    bf16*  qkvb  = (bf16*)w;            w += (size_t)M * 3 * DD * 2;
    bf16*  vtb   = (bf16*)w;            w += (size_t)BB * HH * DK * SS * 2;
    bf16*  attnb = (bf16*)w;            w += nBSD * 2;
    bf16*  attn_sumb = (bf16*)w;        w += nBSD * 2;   // bf16 resid sum 1
    bf16*  ffn_sumb  = (bf16*)w;        w += nBSD * 2;   // bf16 resid sum 2
    bf16*  xb    = (bf16*)w;            w += nBSD * 2;   // reused as out1b
    bf16*  hbuf  = (bf16*)w;            w += (size_t)M * FF * 2;
    bf16*  wqkvb = (bf16*)w;            w += (size_t)3 * DD * DD * 2;
    bf16*  wob   = (bf16*)w;            w += (size_t)DD * DD * 2;
    bf16*  wt1b  = (bf16*)w;            w += (size_t)DD * FF * 2;
    bf16*  wt2b  = (bf16*)w;            w += (size_t)FF * DD * 2;
    float* bqkv  = (float*)w;           w += (size_t)3 * DD * 4;
    bf16*  out1b = xb;

    const dim3 blk(256);

    prep_all<<<dim3(13065), blk, 0, stream>>>(
        Wq, Wk, Wv, Wo, W1, W2, bq, bk, bv, x,
        wqkvb, wob, wt1b, wt2b, bqkv, (bf16x4*)xb);

    // fused QKV projection -> bf16 [M,2304]   (BN=128, m fastest)
    gemm_bf16<128, 1, 0, 0, 0><<<dim3((M / 128) * (3 * DD / 128)), blk, 0, stream>>>(
        xb, wqkvb, bqkv, nullptr, qkvb, M, 3 * DD, DD);

    vtrans<<<dim3(SS / 32, DK / 32, BB * HH), blk, 0, stream>>>(qkvb, vtb);

    // flash attention (bh fastest)
    flash_mfma<<<dim3((SS / 128) * BB * HH), blk, 0, stream>>>(qkvb, vtb, mask, attnb);

    // output projection + residual x(f32) -> bf16 sum   (BN=64)
    gemm_bf16<64, 1, 0, 1, 0><<<dim3((M / 128) * (DD / 64)), blk, 0, stream>>>(
        attnb, wob, bo, x, attn_sumb, M, DD, DD);

    // LN1 -> out1b bf16 only
    layernorm_k<<<dim3(M), blk, 0, stream>>>(attn_sumb, ln1a, ln1b, nullptr, out1b);

    // FFN1 + fast GELU   (BN=128)
    gemm_bf16<128, 1, 1, 0, 0><<<dim3((M / 128) * (FF / 128)), blk, 0, stream>>>(
        out1b, wt1b, b1, nullptr, hbuf, M, FF, DD);

    // FFN2 + residual out1b(bf16) -> bf16 sum   (BN=64)
    gemm_bf16<64, 1, 0, 1, 1><<<dim3((M / 128) * (DD / 64)), blk, 0, stream>>>(
        hbuf, wt2b, b2, out1b, ffn_sumb, M, DD, FF);

    // LN2 -> final fp32 output
    layernorm_k<<<dim3(M), blk, 0, stream>>>(ffn_sumb, ln2a, ln2b, out, nullptr);
}

// Round 9
// 367.248 us; speedup vs baseline: 1.0259x; 1.0259x over previous
//
#include <hip/hip_runtime.h>
#include <hip/hip_bf16.h>
#include <math.h>

// ---------------------------------------------------------------------------
// Problem constants: B=8, S=1024, D=768, F=3072, H=12, d_k=64
// ---------------------------------------------------------------------------
#define BB 8
#define SS 1024
#define DD 768
#define FF 3072
#define HH 12
#define DK 64

typedef __bf16 bf16;
typedef __attribute__((ext_vector_type(8))) __bf16 bf16x8;
typedef __attribute__((ext_vector_type(4))) __bf16 bf16x4;
typedef __attribute__((ext_vector_type(4))) float f32x4;

#define AS1 __attribute__((address_space(1)))
#define AS3 __attribute__((address_space(3)))

// exp(x) = exp2(x*log2e); 1/sqrt(64)=0.125 folded: Q pre-scaled by this in
// the QKV-GEMM epilogue, so flash computes p = exp2(qk + maskbias) directly.
#define EXP2_SCALE 0.18033688011112042f   // 0.125 * log2(e)
#define NLOG2E2    -2.8853900817779268f   // -2 * log2(e)
#define MASK_BIAS  -1.8e8f                // exp2 -> 0 for masked cols

// fast tanh-GELU: 0.5x(1+tanh(u)) == x * sigmoid(2u), exact identity.
__device__ __forceinline__ float gelu_fast(float x) {
    const float u = 0.7978845608028654f * (x + 0.044715f * x * x * x);
    const float e = __builtin_amdgcn_exp2f(u * NLOG2E2);   // exp(-2u)
    return x * __builtin_amdgcn_rcpf(1.0f + e);
}

// ---------------------------------------------------------------------------
// bf16 MFMA GEMM: C[M,N] = A[M,K] @ Bt[N,K]^T + bias (+ R fp32).
// BM=128, BN template {128,64}, BK=64, 256 threads,
// global_load_lds w16 + XOR swizzle, 16x16x32 bf16 MFMA.
// 1-D grid, m-tile FASTEST (stride M/128 = mult of 8 -> same XCD -> A reuse).
// QSC: pre-scale the Q slice (n < DD) by EXP2_SCALE (QKV launch only).
// ---------------------------------------------------------------------------
template<int BN, int OUTB, int GELU_F, int RESID, int QSC>
__global__ __launch_bounds__(256) void gemm_bf16(
    const bf16* __restrict__ A, const bf16* __restrict__ Bt,
    const float* __restrict__ bias, const float* __restrict__ R,
    void* __restrict__ Cout, int M, int N, int K)
{
    constexpr int NTJ   = BN / 32;        // wave n-tiles (4 or 2)
    constexpr int BITER = (BN * 8) / 256; // B staging rounds (4 or 2)

    __shared__ bf16x8 As[1024];           // 128 rows x 8 chunks
    __shared__ bf16x8 Bs[BN * 8];

    const int t    = threadIdx.x;
    const int wave = t >> 6;
    const int lane = t & 63;
    const int mtiles = M >> 7;
    const int m0 = (blockIdx.x % mtiles) * 128;   // m fastest
    const int n0 = (blockIdx.x / mtiles) * BN;
    const int wm = (wave >> 1) * 64;
    const int wn = (wave & 1) * (BN / 2);
    const int col  = lane & 15;
    const int quad = lane >> 4;

    f32x4 acc[4][NTJ] = {};

    const bf16* Abase = A  + (size_t)m0 * K;
    const bf16* Bbase = Bt + (size_t)n0 * K;

    for (int k0 = 0; k0 < K; k0 += 64) {
        if (k0) __syncthreads();

        #pragma unroll
        for (int i = 0; i < 4; ++i) {
            const int chunk = i * 256 + wave * 64 + lane;
            const int r  = chunk >> 3;
            const int kc = (chunk & 7) ^ (r & 7);
            const bf16* ga = Abase + (size_t)r * K + k0 + kc * 8;
            __builtin_amdgcn_global_load_lds((AS1 void*)ga, (AS3 void*)(As + i * 256 + wave * 64), 16, 0, 0);
        }
        #pragma unroll
        for (int i = 0; i < BITER; ++i) {
            const int chunk = i * 256 + wave * 64 + lane;
            const int r  = chunk >> 3;
            const int kc = (chunk & 7) ^ (r & 7);
            const bf16* gb = Bbase + (size_t)r * K + k0 + kc * 8;
            __builtin_amdgcn_global_load_lds((AS1 void*)gb, (AS3 void*)(Bs + i * 256 + wave * 64), 16, 0, 0);
        }
        __syncthreads();

        const bf16* Asp = (const bf16*)As;
        const bf16* Bsp = (const bf16*)Bs;
        #pragma unroll
        for (int ks = 0; ks < 2; ++ks) {
            bf16x8 af[4], bfr[NTJ];
            #pragma unroll
            for (int ti = 0; ti < 4; ++ti) {
                const int r  = wm + ti * 16 + col;
                const int cs = (ks * 4 + quad) ^ (r & 7);
                af[ti] = *(const bf16x8*)(Asp + r * 64 + cs * 8);
            }
            #pragma unroll
            for (int tj = 0; tj < NTJ; ++tj) {
                const int r  = wn + tj * 16 + col;
                const int cs = (ks * 4 + quad) ^ (r & 7);
                bfr[tj] = *(const bf16x8*)(Bsp + r * 64 + cs * 8);
            }
            #pragma unroll
            for (int ti = 0; ti < 4; ++ti)
                #pragma unroll
                for (int tj = 0; tj < NTJ; ++tj)
                    acc[ti][tj] = __builtin_amdgcn_mfma_f32_16x16x32_bf16(
                        af[ti], bfr[tj], acc[ti][tj], 0, 0, 0);
        }
    }

    // block-uniform Q pre-scale (QKV launch: n-tile entirely in/out of Q)
    const float osc = (QSC && n0 < DD) ? EXP2_SCALE : 1.0f;

    float biasv[NTJ];
    #pragma unroll
    for (int tj = 0; tj < NTJ; ++tj) biasv[tj] = bias[n0 + wn + tj * 16 + col];

    #pragma unroll
    for (int ti = 0; ti < 4; ++ti) {
        #pragma unroll
        for (int tj = 0; tj < NTJ; ++tj) {
            const int n = n0 + wn + tj * 16 + col;
            #pragma unroll
            for (int i = 0; i < 4; ++i) {
                const int m = m0 + wm + ti * 16 + quad * 4 + i;
                float v = acc[ti][tj][i] + biasv[tj];
                if (GELU_F) v = gelu_fast(v);
                if (QSC)    v *= osc;
                if (RESID)  v += R[(size_t)m * N + n];
                if (OUTB) ((bf16*)Cout)[(size_t)m * N + n] = (bf16)v;
                else      ((float*)Cout)[(size_t)m * N + n] = v;
            }
        }
    }
}

// ---------------------------------------------------------------------------
// Batched prep: 6 weight transpose+casts, bias concat, x cast — ONE launch.
// ---------------------------------------------------------------------------
__device__ __forceinline__ void tc32(
    const float* __restrict__ src, bf16* __restrict__ dst,
    int R, int C, int c0, int r0, int t)
{
    __shared__ float tile[32][33];
    const int tx = t & 31, ty = t >> 5;
    #pragma unroll
    for (int i = 0; i < 32; i += 8)
        tile[ty + i][tx] = src[(size_t)(r0 + ty + i) * C + c0 + tx];
    __syncthreads();
    #pragma unroll
    for (int i = 0; i < 32; i += 8)
        dst[(size_t)(c0 + ty + i) * R + r0 + tx] = (bf16)tile[tx][ty + i];
}

__global__ __launch_bounds__(256) void prep_all(
    const float* __restrict__ Wq, const float* __restrict__ Wk,
    const float* __restrict__ Wv, const float* __restrict__ Wo,
    const float* __restrict__ W1, const float* __restrict__ W2,
    const float* __restrict__ bq, const float* __restrict__ bk,
    const float* __restrict__ bv, const float* __restrict__ x,
    bf16* __restrict__ wqkvb, bf16* __restrict__ wob,
    bf16* __restrict__ wt1b,  bf16* __restrict__ wt2b,
    float* __restrict__ bqkv, bf16x4* __restrict__ xb)
{
    const int blk = blockIdx.x;
    const int t = threadIdx.x;
    if (blk < 2304) {
        const int job = blk / 576, loc = blk % 576;
        const int c0 = (loc % 24) * 32, r0 = (loc / 24) * 32;
        const float* src = (job == 0) ? Wq : (job == 1) ? Wk : (job == 2) ? Wv : Wo;
        bf16* dst = (job == 3) ? wob : wqkvb + (size_t)job * DD * DD;
        tc32(src, dst, DD, DD, c0, r0, t);
    } else if (blk < 4608) {
        const int loc = blk - 2304;
        tc32(W1, wt1b, DD, FF, (loc % 96) * 32, (loc / 96) * 32, t);
    } else if (blk < 6912) {
        const int loc = blk - 4608;
        tc32(W2, wt2b, FF, DD, (loc % 24) * 32, (loc / 24) * 32, t);
    } else if (blk < 6921) {
        const int i = (blk - 6912) * 256 + t;
        if (i < 3 * DD)
            bqkv[i] = (i < DD) ? bq[i] : (i < 2 * DD ? bk[i - DD] : bv[i - 2 * DD]);
    } else {
        const int i = (blk - 6921) * 256 + t;
        const float4 v = ((const float4*)x)[i];
        bf16x4 o;
        o.x = (bf16)v.x; o.y = (bf16)v.y; o.z = (bf16)v.z; o.w = (bf16)v.w;
        xb[i] = o;
    }
}

// ---------------------------------------------------------------------------
// V transpose: qkvb V-slice [b*S+s][1536+h*64+d] -> vtb[(b*H+h)*64+d][s] bf16
// ---------------------------------------------------------------------------
__global__ __launch_bounds__(256) void vtrans(
    const bf16* __restrict__ qkvb, bf16* __restrict__ vtb)
{
    __shared__ bf16 tile[32][33];
    const int s0 = blockIdx.x * 32, d0 = blockIdx.y * 32;
    const int bh = blockIdx.z;
    const int b = bh / HH, h = bh % HH;
    const int tx = threadIdx.x & 31, ty = threadIdx.x >> 5;
    #pragma unroll
    for (int i = 0; i < 32; i += 8)
        tile[ty + i][tx] = qkvb[(size_t)(b * SS + s0 + ty + i) * 2304 + 1536 + h * DK + d0 + tx];
    __syncthreads();
    #pragma unroll
    for (int i = 0; i < 32; i += 8)
        vtb[(size_t)(bh * DK + d0 + ty + i) * SS + s0 + tx] = tile[tx][ty + i];
}

// ---------------------------------------------------------------------------
// MFMA flash attention, no-max-shift softmax. Block = 128 q-rows of one
// (b,h), 64-col staging (32KB LDS -> high occupancy; R7's 128-col variant
// regressed via occupancy loss). Q arrives pre-scaled by EXP2_SCALE, so
// p = exp2(s + maskbias). Row-sums via ones-MFMA (l lands in C-layout on
// exactly the lane that stores q -> no shfl reduction, no scalar adds).
// 1-D grid, bh FASTEST (stride 96 -> same XCD -> K/V L2 reuse).
// ---------------------------------------------------------------------------
__global__ __launch_bounds__(256) void flash_mfma(
    const bf16* __restrict__ qkvb,   // [M,2304] bf16 (Q slice pre-scaled)
    const bf16* __restrict__ vtb,    // [96*64, 1024] bf16
    const int*  __restrict__ mask,   // [B*S]
    bf16* __restrict__ O)            // [M,768] bf16
{
    __shared__ bf16x8 Ks[512];        // 64 c-rows x 8 swizzled d-chunks (8 KB)
    __shared__ bf16x8 Vs[512];        // 64 d-rows x 8 swizzled c-chunks (8 KB)
    __shared__ bf16   Ps[4 * 32 * 64];// per-wave 32x64 swizzled (16 KB)

    const int t    = threadIdx.x;
    const int wave = t >> 6;
    const int lane = t & 63;
    const int col  = lane & 15;
    const int quad = lane >> 4;
    const int bh = blockIdx.x % (BB * HH);       // bh fastest
    const int q0 = (blockIdx.x / (BB * HH)) * 128;
    const int b  = bh / HH;
    const int h  = bh % HH;

    bf16x8 aq[2][2];
    #pragma unroll
    for (int mi = 0; mi < 2; ++mi)
        #pragma unroll
        for (int ks = 0; ks < 2; ++ks)
            aq[mi][ks] = *(const bf16x8*)(qkvb
                + (size_t)(b * SS + q0 + wave * 32 + mi * 16 + col) * 2304
                + h * DK + ks * 32 + quad * 8);

    // ones B-fragment for row-sum MFMA
    bf16x8 ones;
    #pragma unroll
    for (int j = 0; j < 8; ++j) ones[j] = (bf16)1.0f;

    f32x4 o[2][4] = {};
    f32x4 o_l[2] = {};            // row-sum accumulators (C-layout)

    bf16* Pw = Ps + wave * 2048;

    for (int c0 = 0; c0 < SS; c0 += 64) {
        if (c0) __syncthreads();

        #pragma unroll
        for (int i = 0; i < 2; ++i) {
            const int s  = i * 256 + wave * 64 + lane;
            const int r  = s >> 3;
            const int kc = (s & 7) ^ (r & 7);
            const bf16* gk = qkvb + (size_t)(b * SS + c0 + r) * 2304 + DD + h * DK + kc * 8;
            __builtin_amdgcn_global_load_lds((AS1 void*)gk, (AS3 void*)(Ks + i * 256 + wave * 64), 16, 0, 0);
            const bf16* gv = vtb + (size_t)(bh * DK + r) * SS + c0 + kc * 8;
            __builtin_amdgcn_global_load_lds((AS1 void*)gv, (AS3 void*)(Vs + i * 256 + wave * 64), 16, 0, 0);
        }
        __syncthreads();

        // ---- S = Q K^T ----
        const bf16* Ksp = (const bf16*)Ks;
        f32x4 s4[2][4] = {};
        {
            bf16x8 kf[2][4];
            #pragma unroll
            for (int ks = 0; ks < 2; ++ks)
                #pragma unroll
                for (int tj = 0; tj < 4; ++tj) {
                    const int r  = tj * 16 + col;
                    const int sl = (ks * 4 + quad) ^ (r & 7);
                    kf[ks][tj] = *(const bf16x8*)(Ksp + r * 64 + sl * 8);
                }
            #pragma unroll
            for (int mi = 0; mi < 2; ++mi)
                #pragma unroll
                for (int ks = 0; ks < 2; ++ks)
                    #pragma unroll
                    for (int tj = 0; tj < 4; ++tj)
                        s4[mi][tj] = __builtin_amdgcn_mfma_f32_16x16x32_bf16(
                            aq[mi][ks], kf[ks][tj], s4[mi][tj], 0, 0, 0);
        }

        // ---- P = exp2(S + maskbias) -> wave-private LDS ----
        float addb[4];
        #pragma unroll
        for (int tj = 0; tj < 4; ++tj)
            addb[tj] = mask[b * SS + c0 + tj * 16 + col] ? 0.0f : MASK_BIAS;

        #pragma unroll
        for (int mi = 0; mi < 2; ++mi)
            #pragma unroll
            for (int i = 0; i < 4; ++i) {
                const int rf = mi * 16 + quad * 4 + i;
                #pragma unroll
                for (int tj = 0; tj < 4; ++tj) {
                    const float p = __builtin_amdgcn_exp2f(s4[mi][tj][i] + addb[tj]);
                    const int c  = tj * 16 + col;
                    const int sl = ((c >> 3) ^ (rf & 7));
                    Pw[rf * 64 + sl * 8 + (c & 7)] = (bf16)p;
                }
            }

        // ---- O += P V ;  l += P @ 1 (ones-MFMA) ----
        const bf16* Vsp = (const bf16*)Vs;
        bf16x8 vf[2][4];
        #pragma unroll
        for (int ks = 0; ks < 2; ++ks)
            #pragma unroll
            for (int tj = 0; tj < 4; ++tj) {
                const int r  = tj * 16 + col;
                const int sl = (ks * 4 + quad) ^ (r & 7);
                vf[ks][tj] = *(const bf16x8*)(Vsp + r * 64 + sl * 8);
            }
        #pragma unroll
        for (int mi = 0; mi < 2; ++mi) {
            bf16x8 pf[2];
            #pragma unroll
            for (int ks = 0; ks < 2; ++ks) {
                const int rf = mi * 16 + col;
                const int sl = (ks * 4 + quad) ^ (rf & 7);
                pf[ks] = *(const bf16x8*)(Pw + rf * 64 + sl * 8);
            }
            #pragma unroll
            for (int ks = 0; ks < 2; ++ks) {
                #pragma unroll
                for (int tj = 0; tj < 4; ++tj)
                    o[mi][tj] = __builtin_amdgcn_mfma_f32_16x16x32_bf16(
                        pf[ks], vf[ks][tj], o[mi][tj], 0, 0, 0);
                o_l[mi] = __builtin_amdgcn_mfma_f32_16x16x32_bf16(
                    pf[ks], ones, o_l[mi], 0, 0, 0);
            }
        }
    }

    // ---- finalize: l already per-lane in C-layout; divide, store ----
    #pragma unroll
    for (int mi = 0; mi < 2; ++mi)
        #pragma unroll
        for (int i = 0; i < 4; ++i) {
            const float inv = 1.0f / o_l[mi][i];
            const int q = q0 + wave * 32 + mi * 16 + quad * 4 + i;
            #pragma unroll
            for (int tj = 0; tj < 4; ++tj)
                O[(size_t)(b * SS + q) * DD + h * DK + tj * 16 + col] =
                    (bf16)(o[mi][tj][i] * inv);
        }
}

// ---------------------------------------------------------------------------
// LayerNorm (torch-style: unbiased var, eps on std). fp32 in.
// Optional fp32 and bf16 outputs.
// ---------------------------------------------------------------------------
__global__ __launch_bounds__(256) void layernorm_k(
    const float* __restrict__ X,
    const float* __restrict__ ga, const float* __restrict__ gb,
    float* __restrict__ out, bf16* __restrict__ outb)
{
    __shared__ float red[4];
    const int row = blockIdx.x;
    const int t   = threadIdx.x;
    const float* x = X + (size_t)row * DD;

    float v[3];
    #pragma unroll
    for (int i = 0; i < 3; ++i) v[i] = x[t + i * 256];

    float s = v[0] + v[1] + v[2];
    #pragma unroll
    for (int off = 32; off > 0; off >>= 1) s += __shfl_down(s, off, 64);
    if ((t & 63) == 0) red[t >> 6] = s;
    __syncthreads();
    const float mean = (red[0] + red[1] + red[2] + red[3]) * (1.0f / 768.0f);
    __syncthreads();

    float sq = 0.f;
    #pragma unroll
    for (int i = 0; i < 3; ++i) { const float d = v[i] - mean; sq += d * d; }
    #pragma unroll
    for (int off = 32; off > 0; off >>= 1) sq += __shfl_down(sq, off, 64);
    if ((t & 63) == 0) red[t >> 6] = sq;
    __syncthreads();
    const float var = (red[0] + red[1] + red[2] + red[3]) * (1.0f / 767.0f);
    const float inv = 1.0f / (sqrtf(var) + 1e-6f);

    #pragma unroll
    for (int i = 0; i < 3; ++i) {
        const int c = t + i * 256;
        const float r = ga[c] * (v[i] - mean) * inv + gb[c];
        if (out)  out[(size_t)row * DD + c] = r;
        if (outb) outb[(size_t)row * DD + c] = (bf16)r;
    }
}

// ---------------------------------------------------------------------------
// Launch
// ---------------------------------------------------------------------------
extern "C" void kernel_launch(void* const* d_in, const int* in_sizes, int n_in,
                              void* d_out, int out_size, void* d_ws, size_t ws_size,
                              hipStream_t stream)
{
    const float* x    = (const float*)d_in[0];
    const int*   mask = (const int*)  d_in[1];
    const float* Wq   = (const float*)d_in[2];
    const float* bq   = (const float*)d_in[3];
    const float* Wk   = (const float*)d_in[4];
    const float* bk   = (const float*)d_in[5];
    const float* Wv   = (const float*)d_in[6];
    const float* bv   = (const float*)d_in[7];
    const float* Wo   = (const float*)d_in[8];
    const float* bo   = (const float*)d_in[9];
    const float* W1   = (const float*)d_in[10];
    const float* b1   = (const float*)d_in[11];
    const float* W2   = (const float*)d_in[12];
    const float* b2   = (const float*)d_in[13];
    const float* ln1a = (const float*)d_in[14];
    const float* ln1b = (const float*)d_in[15];
    const float* ln2a = (const float*)d_in[16];
    const float* ln2b = (const float*)d_in[17];
    float* out = (float*)d_out;

    const int M = BB * SS;                       // 8192
    const size_t nBSD = (size_t)M * DD;

    char* w = (char*)d_ws;
    bf16*  qkvb  = (bf16*)w;            w += (size_t)M * 3 * DD * 2;
    bf16*  vtb   = (bf16*)w;            w += (size_t)BB * HH * DK * SS * 2;
    bf16*  attnb = (bf16*)w;            w += nBSD * 2;
    float* attn_sum = (float*)w;        w += nBSD * 4;
    float* out1  = (float*)w;           w += nBSD * 4;
    float* ffn_sum = (float*)w;         w += nBSD * 4;
    bf16*  xb    = (bf16*)w;            w += nBSD * 2;
    bf16*  hbuf  = (bf16*)w;            w += (size_t)M * FF * 2;
    bf16*  wqkvb = (bf16*)w;            w += (size_t)3 * DD * DD * 2;
    bf16*  wob   = (bf16*)w;            w += (size_t)DD * DD * 2;
    bf16*  wt1b  = (bf16*)w;            w += (size_t)DD * FF * 2;
    bf16*  wt2b  = (bf16*)w;            w += (size_t)FF * DD * 2;
    float* bqkv  = (float*)w;           w += (size_t)3 * DD * 4;
    bf16*  out1b = xb;

    const dim3 blk(256);

    prep_all<<<dim3(13065), blk, 0, stream>>>(
        Wq, Wk, Wv, Wo, W1, W2, bq, bk, bv, x,
        wqkvb, wob, wt1b, wt2b, bqkv, (bf16x4*)xb);

    // fused QKV projection -> bf16 [M,2304], Q slice pre-scaled (QSC=1)
    gemm_bf16<128, 1, 0, 0, 1><<<dim3((M / 128) * (3 * DD / 128)), blk, 0, stream>>>(
        xb, wqkvb, bqkv, nullptr, qkvb, M, 3 * DD, DD);

    vtrans<<<dim3(SS / 32, DK / 32, BB * HH), blk, 0, stream>>>(qkvb, vtb);

    // flash attention (bh fastest)
    flash_mfma<<<dim3((SS / 128) * BB * HH), blk, 0, stream>>>(qkvb, vtb, mask, attnb);

    // output projection + residual x -> fp32   (BN=64)
    gemm_bf16<64, 0, 0, 1, 0><<<dim3((M / 128) * (DD / 64)), blk, 0, stream>>>(
        attnb, wob, bo, x, attn_sum, M, DD, DD);

    // LN1 -> out1 fp32 + out1b bf16
    layernorm_k<<<dim3(M), blk, 0, stream>>>(attn_sum, ln1a, ln1b, out1, out1b);

    // FFN1 + fast GELU   (BN=128)
    gemm_bf16<128, 1, 1, 0, 0><<<dim3((M / 128) * (FF / 128)), blk, 0, stream>>>(
        out1b, wt1b, b1, nullptr, hbuf, M, FF, DD);

    // FFN2 + residual out1 -> fp32   (BN=64)
    gemm_bf16<64, 0, 0, 1, 0><<<dim3((M / 128) * (DD / 64)), blk, 0, stream>>>(
        hbuf, wt2b, b2, out1, ffn_sum, M, DD, FF);

    // LN2 -> final fp32 output
    layernorm_k<<<dim3(M), blk, 0, stream>>>(ffn_sum, ln2a, ln2b, out, nullptr);
}